// Round 19
// baseline (102.077 us; speedup 1.0000x reference)
//
#include <hip/hip_runtime.h>
#include <hip/hip_bf16.h>

#define B_ROWS 131072
#define H 128
#define SLAB 16
#define NSLAB 16                 // 256 rows per block strip
#define NBLK 512

typedef __bf16 bf16x8 __attribute__((ext_vector_type(8)));
typedef float f32x4 __attribute__((ext_vector_type(4)));

#define LOG2E 1.4426950408889634f
#define GLP(p) ((const __attribute__((address_space(1))) void*)(p))
#define LLP(p) ((__attribute__((address_space(3))) void*)(p))

__device__ __forceinline__ float fast_sigmoid(float v) {
    return __builtin_amdgcn_rcpf(1.0f + __builtin_amdgcn_exp2f(-LOG2E * v));
}
__device__ __forceinline__ float fast_tanh(float v) {
    return 1.0f - 2.0f * __builtin_amdgcn_rcpf(1.0f + __builtin_amdgcn_exp2f(2.0f * LOG2E * v));
}

struct WPtrs {
    const float* wx[4];
    const float* wh[4];
    const float* bx[4];
    const float* bh[4];
};

// Wcat[n][k]: n = gate*128 + unit, k in [0,256) = [X-k | h-k]. bsum[n] = bx+bh.
__global__ __launch_bounds__(256) void prep_weights(WPtrs p, __bf16* __restrict__ wcat,
                                                    float* __restrict__ bsum) {
    int n = blockIdx.x;
    int k = threadIdx.x;
    int g = n >> 7, r = n & 127;
    float v = (k < H) ? p.wx[g][r * H + k] : p.wh[g][r * H + (k - H)];
    wcat[n * 256 + k] = (__bf16)v;
    if (k == 0) bsum[n] = p.bx[g][r] + p.bh[g][r];
}

// R19: DMA-staged pipeline. The R3..R18 plateau (88-107us, HBM stuck at 2.2TB/s)
// is a memory-issue DUTY-CYCLE problem: register-staged prefetch caps at ~1
// cadence depth (VGPR budget), so loads burst then go silent. Fix: A-slab staged
// HBM->LDS as f32 via global_load_lds (no staging VGPRs, no write phase), 4-deep
// slab buffers, counted s_waitcnt vmcnt(6) (FIFO-safe: >=6 younger store/DMA ops
// are issued before every wait, incl. tail iters) -> 3 slabs/block continuously
// in flight. Weights pinned->AGPR (R13), coalesced f32x4 epilogue (R18).
// 64KB LDS + ~218 unified regs -> 2 blocks/CU co-resident = 16 waves/CU.
// LDS slot-swizzle done by pre-swizzling the per-lane GLOBAL address (m173).
__global__ __launch_bounds__(512, 1) void lstm_fused(
    const float* __restrict__ X, const float* __restrict__ Hp, const float* __restrict__ Cp,
    const __bf16* __restrict__ Wcat, const float* __restrict__ Bsum,
    float* __restrict__ out)
{
    __shared__ char abuf[4][SLAB * 1024];   // 4 x 16 KB f32 [X|h] slabs, slot-XOR swizzled

    const int t = threadIdx.x;
    const int lane = t & 63;
    const int wv = t >> 6;                  // 0..7: unit group of 16
    const int l16 = lane & 15;              // batch row within slab / W unit-row
    const int kg = lane >> 4;               // 0..3
    const long base = (long)blockIdx.x * (SLAB * NSLAB);
    const long c_off = (long)B_ROWS * H;
    const int ubase = wv * 16 + kg * 4;     // lane's 4 consecutive units (epilogue)

    // ---- W fragments (A-operand role), pinned -> AGPR ----
    bf16x8 wreg[4][8];
    {
        const __bf16* wb = Wcat + ((long)(wv * 16 + l16)) * 256 + kg * 8;
#pragma unroll
        for (int g = 0; g < 4; ++g)
#pragma unroll
            for (int kc = 0; kc < 8; ++kc) {
                wreg[g][kc] = *(const bf16x8*)(wb + g * (128 * 256) + kc * 32);
                asm volatile("" : "+v"(wreg[g][kc]));
            }
    }
    f32x4 bias4[4];
#pragma unroll
    for (int g = 0; g < 4; ++g)
        bias4[g] = *(const f32x4*)(Bsum + g * H + ubase);

    // ---- DMA one slab (16 rows x 1KB) into buf; wave covers rows wv*2, wv*2+1 ----
    // LDS phys slot = lane (HW: uniform base + lane*16); logical slot = lane^(r&7)
    // (XOR<=7 keeps bit5 -> X/h split preserved). Read side XORs the same way.
    auto dma_slab = [&](long srow, int bufi) {
        char* buf = abuf[bufi];
#pragma unroll
        for (int q = 0; q < 2; ++q) {
            int r = wv * 2 + q;
            int ls = lane ^ (r & 7);
            const float* src = (ls < 32) ? (X + (srow + r) * H + ls * 4)
                                         : (Hp + (srow + r) * H + (ls - 32) * 4);
            __builtin_amdgcn_global_load_lds(GLP(src), LLP(buf + r * 1024), 16, 0, 0);
        }
    };
    auto load_cp = [&](f32x4* c, long srow) {
        *c = *(const f32x4*)(Cp + (srow + l16) * (long)H + ubase);
    };

    f32x4 cpv, cpn;

    // prologue: fill 3 slabs, drain once
    dma_slab(base, 0);
    dma_slab(base + SLAB, 1);
    dma_slab(base + 2 * SLAB, 2);
    load_cp(&cpv, base);
    asm volatile("s_waitcnt vmcnt(0)\n\ts_barrier" ::: "memory");

    for (int s = 0; s < NSLAB; ++s) {
        const long srow = base + (long)s * SLAB;

        if (s > 0)   // counted wait: own DMA(s) done (FIFO; >=6 younger stores/DMA issued)
            asm volatile("s_waitcnt vmcnt(6)\n\ts_barrier" ::: "memory");

        if (s + 3 < NSLAB) dma_slab(srow + 3 * SLAB, (s + 3) & 3);
        load_cp(&cpn, (s + 1 < NSLAB) ? srow + SLAB : srow);

        const char* ac = abuf[s & 3];
        f32x4 acc[4] = {};
#pragma unroll
        for (int kc = 0; kc < 8; ++kc) {
            const char* rb = ac + l16 * 1024;
            int p0 = ((kc * 8 + kg * 2)     ^ (l16 & 7)) * 16;
            int p1 = ((kc * 8 + kg * 2 + 1) ^ (l16 & 7)) * 16;
            f32x4 fa = *(const f32x4*)(rb + p0);
            f32x4 fb = *(const f32x4*)(rb + p1);
            union { __bf16 e[8]; bf16x8 v; } u;
            u.e[0] = (__bf16)fa[0]; u.e[1] = (__bf16)fa[1];
            u.e[2] = (__bf16)fa[2]; u.e[3] = (__bf16)fa[3];
            u.e[4] = (__bf16)fb[0]; u.e[5] = (__bf16)fb[1];
            u.e[6] = (__bf16)fb[2]; u.e[7] = (__bf16)fb[3];
            bf16x8 xf = u.v;
#pragma unroll
            for (int g = 0; g < 4; ++g)
                acc[g] = __builtin_amdgcn_mfma_f32_16x16x32_bf16(wreg[g][kc], xf, acc[g], 0, 0, 0);
        }

        // epilogue: lane = batch row (srow+l16), units ubase..ubase+3 -> f32x4 I/O
        const long brow = srow + l16;
        f32x4 hv, cv;
#pragma unroll
        for (int r = 0; r < 4; ++r) {
            float fg = acc[0][r] + bias4[0][r];
            float ig = acc[1][r] + bias4[1][r];
            float cg = acc[2][r] + bias4[2][r];
            float og = acc[3][r] + bias4[3][r];
            float ft = fast_sigmoid(fg);
            float it = fast_sigmoid(ig);
            float cc = fast_tanh(cg);
            float ot = fast_sigmoid(og);
            float ct = ft * cpv[r] + it * cc;
            float ht = ot * fast_tanh(ct);
            hv[r] = ht;
            cv[r] = ct;
        }
        *(f32x4*)(out + brow * H + ubase) = hv;
        *(f32x4*)(out + c_off + brow * H + ubase) = cv;
        cpv = cpn;
    }
}

extern "C" void kernel_launch(void* const* d_in, const int* in_sizes, int n_in,
                              void* d_out, int out_size, void* d_ws, size_t ws_size,
                              hipStream_t stream) {
    const float* X  = (const float*)d_in[0];
    const float* Hp = (const float*)d_in[1];
    const float* Cp = (const float*)d_in[2];
    WPtrs p;
    p.wx[0] = (const float*)d_in[3];  p.bx[0] = (const float*)d_in[4];
    p.wh[0] = (const float*)d_in[5];  p.bh[0] = (const float*)d_in[6];
    p.wx[1] = (const float*)d_in[7];  p.bx[1] = (const float*)d_in[8];
    p.wh[1] = (const float*)d_in[9];  p.bh[1] = (const float*)d_in[10];
    p.wx[2] = (const float*)d_in[11]; p.bx[2] = (const float*)d_in[12];
    p.wh[2] = (const float*)d_in[13]; p.bh[2] = (const float*)d_in[14];
    p.wx[3] = (const float*)d_in[15]; p.bx[3] = (const float*)d_in[16];
    p.wh[3] = (const float*)d_in[17]; p.bh[3] = (const float*)d_in[18];

    __bf16* wcat = (__bf16*)d_ws;
    float*  bsum = (float*)((char*)d_ws + 512 * 256 * 2);

    prep_weights<<<512, 256, 0, stream>>>(p, wcat, bsum);
    lstm_fused<<<NBLK, 512, 0, stream>>>(X, Hp, Cp, wcat, bsum, (float*)d_out);
}